// Round 1
// baseline (196.200 us; speedup 1.0000x reference)
//
#include <hip/hip_runtime.h>
#include <math.h>

#define HDIM 4096
#define VDIM 32000

__device__ inline float wave_reduce_sum(float v) {
    #pragma unroll
    for (int off = 32; off > 0; off >>= 1)
        v += __shfl_down(v, off, 64);
    return v;
}

__device__ inline float wave_reduce_max(float v) {
    #pragma unroll
    for (int off = 32; off > 0; off >>= 1)
        v = fmaxf(v, __shfl_down(v, off, 64));
    return v;
}

// One block per output row. Wave g (of 4) computes gate g for this row:
// dot(w_x_g[row,:], x) + dot(w_h_g[row,:], h) + b_g[row].
// Thread 0 then applies the LSTM cell update and writes h_t, c_t.
__global__ __launch_bounds__(256) void lstm_gates_kernel(
    const float* __restrict__ prev_h, const float* __restrict__ prev_c,
    const float* __restrict__ x_t,
    const float* __restrict__ w_xf, const float* __restrict__ w_hf, const float* __restrict__ b_f,
    const float* __restrict__ w_xi, const float* __restrict__ w_hi, const float* __restrict__ b_i,
    const float* __restrict__ w_xg, const float* __restrict__ w_hg, const float* __restrict__ b_g,
    const float* __restrict__ w_xo, const float* __restrict__ w_ho, const float* __restrict__ b_o,
    float* __restrict__ out)
{
    const int row  = blockIdx.x;
    const int wave = threadIdx.x >> 6;
    const int lane = threadIdx.x & 63;

    const float* wx; const float* wh; const float* bb;
    if      (wave == 0) { wx = w_xf; wh = w_hf; bb = b_f; }
    else if (wave == 1) { wx = w_xi; wh = w_hi; bb = b_i; }
    else if (wave == 2) { wx = w_xg; wh = w_hg; bb = b_g; }
    else                { wx = w_xo; wh = w_ho; bb = b_o; }
    wx += (size_t)row * HDIM;
    wh += (size_t)row * HDIM;

    float acc = 0.f;
    #pragma unroll 4
    for (int j = lane * 4; j < HDIM; j += 64 * 4) {
        float4 a = *reinterpret_cast<const float4*>(wx + j);
        float4 v = *reinterpret_cast<const float4*>(x_t + j);
        acc += a.x * v.x + a.y * v.y + a.z * v.z + a.w * v.w;
        float4 b = *reinterpret_cast<const float4*>(wh + j);
        float4 u = *reinterpret_cast<const float4*>(prev_h + j);
        acc += b.x * u.x + b.y * u.y + b.z * u.z + b.w * u.w;
    }
    acc = wave_reduce_sum(acc);

    __shared__ float g4[4];
    if (lane == 0) g4[wave] = acc + bb[row];
    __syncthreads();
    if (threadIdx.x == 0) {
        float ft = 1.f / (1.f + expf(-g4[0]));
        float it = 1.f / (1.f + expf(-g4[1]));
        float gt = tanhf(g4[2]);
        float ot = 1.f / (1.f + expf(-g4[3]));
        float c  = ft * prev_c[row] + it * gt;
        float h  = ot * tanhf(c);
        out[row]        = h;   // h_t
        out[HDIM + row] = c;   // c_t
    }
}

// Wave-per-row logits: logit[r] = dot(w_hy[r,:], h) + b_y[r]
__global__ __launch_bounds__(256) void logits_kernel(
    const float* __restrict__ w_hy, const float* __restrict__ b_y,
    const float* __restrict__ h, float* __restrict__ logits)
{
    const int row  = blockIdx.x * 4 + (threadIdx.x >> 6);
    const int lane = threadIdx.x & 63;
    const float* w = w_hy + (size_t)row * HDIM;

    float acc = 0.f;
    #pragma unroll 4
    for (int j = lane * 4; j < HDIM; j += 64 * 4) {
        float4 a = *reinterpret_cast<const float4*>(w + j);
        float4 v = *reinterpret_cast<const float4*>(h + j);
        acc += a.x * v.x + a.y * v.y + a.z * v.z + a.w * v.w;
    }
    acc = wave_reduce_sum(acc);
    if (lane == 0) logits[row] = acc + b_y[row];
}

// Single block: compute max and 1/sum(exp(l - max)) over all V logits.
__global__ __launch_bounds__(1024) void softmax_stats_kernel(
    const float* __restrict__ logits, float* __restrict__ stats)
{
    __shared__ float sm[16];
    const int tid = threadIdx.x;

    float m = -INFINITY;
    for (int i = tid; i < VDIM; i += 1024) m = fmaxf(m, logits[i]);
    m = wave_reduce_max(m);
    if ((tid & 63) == 0) sm[tid >> 6] = m;
    __syncthreads();
    if (tid < 16) {
        m = sm[tid];
        #pragma unroll
        for (int off = 8; off > 0; off >>= 1) m = fmaxf(m, __shfl_down(m, off, 64));
        if (tid == 0) sm[0] = m;
    }
    __syncthreads();
    m = sm[0];
    __syncthreads();

    float s = 0.f;
    for (int i = tid; i < VDIM; i += 1024) s += expf(logits[i] - m);
    s = wave_reduce_sum(s);
    __shared__ float sm2[16];
    if ((tid & 63) == 0) sm2[tid >> 6] = s;
    __syncthreads();
    if (tid < 16) {
        s = sm2[tid];
        #pragma unroll
        for (int off = 8; off > 0; off >>= 1) s += __shfl_down(s, off, 64);
        if (tid == 0) { stats[0] = m; stats[1] = 1.f / s; }
    }
}

__global__ __launch_bounds__(256) void softmax_norm_kernel(
    const float* __restrict__ logits, const float* __restrict__ stats,
    float* __restrict__ y)
{
    const int i = blockIdx.x * 256 + threadIdx.x;
    if (i < VDIM) y[i] = expf(logits[i] - stats[0]) * stats[1];
}

extern "C" void kernel_launch(void* const* d_in, const int* in_sizes, int n_in,
                              void* d_out, int out_size, void* d_ws, size_t ws_size,
                              hipStream_t stream)
{
    const float* prev_h = (const float*)d_in[0];
    const float* prev_c = (const float*)d_in[1];
    const float* x_t    = (const float*)d_in[2];
    const float* w_xf   = (const float*)d_in[3];
    const float* w_hf   = (const float*)d_in[4];
    const float* b_f    = (const float*)d_in[5];
    const float* w_xi   = (const float*)d_in[6];
    const float* w_hi   = (const float*)d_in[7];
    const float* b_i    = (const float*)d_in[8];
    const float* w_xg   = (const float*)d_in[9];
    const float* w_hg   = (const float*)d_in[10];
    const float* b_g    = (const float*)d_in[11];
    const float* w_xo   = (const float*)d_in[12];
    const float* w_ho   = (const float*)d_in[13];
    const float* b_o    = (const float*)d_in[14];
    const float* w_hy   = (const float*)d_in[15];
    const float* b_y    = (const float*)d_in[16];

    float* out = (float*)d_out;
    float* h_t = out;              // [0, H)
    float* y_t = out + 2 * HDIM;   // [2H, 2H+V)

    float* logits = (float*)d_ws;  // V floats
    float* stats  = logits + VDIM; // 2 floats

    lstm_gates_kernel<<<HDIM, 256, 0, stream>>>(
        prev_h, prev_c, x_t,
        w_xf, w_hf, b_f, w_xi, w_hi, b_i,
        w_xg, w_hg, b_g, w_xo, w_ho, b_o, out);

    logits_kernel<<<VDIM / 4, 256, 0, stream>>>(w_hy, b_y, h_t, logits);

    softmax_stats_kernel<<<1, 1024, 0, stream>>>(logits, stats);

    softmax_norm_kernel<<<(VDIM + 255) / 256, 256, 0, stream>>>(logits, stats, y_t);
}

// Round 2
// 190.358 us; speedup vs baseline: 1.0307x; 1.0307x over previous
//
#include <hip/hip_runtime.h>
#include <math.h>

#define HDIM 4096
#define VDIM 32000
#define NPART 125   // 125 * 256 == 32000

__device__ inline float wave_reduce_sum(float v) {
    #pragma unroll
    for (int off = 32; off > 0; off >>= 1)
        v += __shfl_down(v, off, 64);
    return v;
}

__device__ inline float wave_reduce_max(float v) {
    #pragma unroll
    for (int off = 32; off > 0; off >>= 1)
        v = fmaxf(v, __shfl_down(v, off, 64));
    return v;
}

// One block per output row. x_t and prev_h staged in LDS once per block;
// wave g computes gate g: dot(w_x_g[row,:], x) + dot(w_h_g[row,:], h) + b.
__global__ __launch_bounds__(256) void lstm_gates_kernel(
    const float* __restrict__ prev_h, const float* __restrict__ prev_c,
    const float* __restrict__ x_t,
    const float* __restrict__ w_xf, const float* __restrict__ w_hf, const float* __restrict__ b_f,
    const float* __restrict__ w_xi, const float* __restrict__ w_hi, const float* __restrict__ b_i,
    const float* __restrict__ w_xg, const float* __restrict__ w_hg, const float* __restrict__ b_g,
    const float* __restrict__ w_xo, const float* __restrict__ w_ho, const float* __restrict__ b_o,
    float* __restrict__ out)
{
    __shared__ float s_x[HDIM];
    __shared__ float s_h[HDIM];
    for (int i = threadIdx.x * 4; i < HDIM; i += 256 * 4) {
        *reinterpret_cast<float4*>(&s_x[i]) = *reinterpret_cast<const float4*>(&x_t[i]);
        *reinterpret_cast<float4*>(&s_h[i]) = *reinterpret_cast<const float4*>(&prev_h[i]);
    }
    __syncthreads();

    const int row  = blockIdx.x;
    const int wave = threadIdx.x >> 6;
    const int lane = threadIdx.x & 63;

    const float* wx; const float* wh; const float* bb;
    if      (wave == 0) { wx = w_xf; wh = w_hf; bb = b_f; }
    else if (wave == 1) { wx = w_xi; wh = w_hi; bb = b_i; }
    else if (wave == 2) { wx = w_xg; wh = w_hg; bb = b_g; }
    else                { wx = w_xo; wh = w_ho; bb = b_o; }
    wx += (size_t)row * HDIM;
    wh += (size_t)row * HDIM;

    float accx = 0.f, acch = 0.f;
    #pragma unroll 4
    for (int j = lane * 4; j < HDIM; j += 64 * 4) {
        float4 a = *reinterpret_cast<const float4*>(wx + j);
        float4 v = *reinterpret_cast<const float4*>(&s_x[j]);
        accx += a.x * v.x + a.y * v.y + a.z * v.z + a.w * v.w;
        float4 b = *reinterpret_cast<const float4*>(wh + j);
        float4 u = *reinterpret_cast<const float4*>(&s_h[j]);
        acch += b.x * u.x + b.y * u.y + b.z * u.z + b.w * u.w;
    }
    float acc = wave_reduce_sum(accx + acch);

    __shared__ float g4[4];
    if (lane == 0) g4[wave] = acc + bb[row];
    __syncthreads();
    if (threadIdx.x == 0) {
        float ft = 1.f / (1.f + expf(-g4[0]));
        float it = 1.f / (1.f + expf(-g4[1]));
        float gt = tanhf(g4[2]);
        float ot = 1.f / (1.f + expf(-g4[3]));
        float c  = ft * prev_c[row] + it * gt;
        float h  = ot * tanhf(c);
        out[row]        = h;   // h_t
        out[HDIM + row] = c;   // c_t
    }
}

// Wave-per-row logits, h staged in LDS: logit[r] = dot(w_hy[r,:], h) + b_y[r]
__global__ __launch_bounds__(256) void logits_kernel(
    const float* __restrict__ w_hy, const float* __restrict__ b_y,
    const float* __restrict__ h, float* __restrict__ logits)
{
    __shared__ float s_h[HDIM];
    for (int i = threadIdx.x * 4; i < HDIM; i += 256 * 4)
        *reinterpret_cast<float4*>(&s_h[i]) = *reinterpret_cast<const float4*>(&h[i]);
    __syncthreads();

    const int row  = blockIdx.x * 4 + (threadIdx.x >> 6);
    const int lane = threadIdx.x & 63;
    const float* w = w_hy + (size_t)row * HDIM;

    float acc0 = 0.f, acc1 = 0.f;
    #pragma unroll 4
    for (int j = lane * 8; j < HDIM; j += 64 * 8) {
        float4 a = *reinterpret_cast<const float4*>(w + j);
        float4 v = *reinterpret_cast<const float4*>(&s_h[j]);
        acc0 += a.x * v.x + a.y * v.y + a.z * v.z + a.w * v.w;
        float4 b = *reinterpret_cast<const float4*>(w + j + 4);
        float4 u = *reinterpret_cast<const float4*>(&s_h[j + 4]);
        acc1 += b.x * u.x + b.y * u.y + b.z * u.z + b.w * u.w;
    }
    float acc = wave_reduce_sum(acc0 + acc1);
    if (lane == 0) logits[row] = acc + b_y[row];
}

// 125 blocks x 256 threads: per-block online (max, sum-exp) partials.
__global__ __launch_bounds__(256) void softmax_partial_kernel(
    const float* __restrict__ logits, float2* __restrict__ part)
{
    const int wave = threadIdx.x >> 6;
    const int lane = threadIdx.x & 63;
    float v = logits[blockIdx.x * 256 + threadIdx.x];

    float m = wave_reduce_max(v);
    __shared__ float sm[4];
    if (lane == 0) sm[wave] = m;
    __syncthreads();
    m = fmaxf(fmaxf(sm[0], sm[1]), fmaxf(sm[2], sm[3]));

    float s = wave_reduce_sum(expf(v - m));
    __shared__ float ss[4];
    if (lane == 0) ss[wave] = s;
    __syncthreads();
    if (threadIdx.x == 0)
        part[blockIdx.x] = make_float2(m, ss[0] + ss[1] + ss[2] + ss[3]);
}

// 1 block, 128 threads: combine 125 partials -> stats[0]=max, stats[1]=1/sum
__global__ __launch_bounds__(128) void softmax_combine_kernel(
    const float2* __restrict__ part, float* __restrict__ stats)
{
    const int tid = threadIdx.x;
    float2 p = (tid < NPART) ? part[tid] : make_float2(-1e30f, 0.f);

    float m = wave_reduce_max(p.x);
    __shared__ float sm[2];
    if ((tid & 63) == 0) sm[tid >> 6] = m;
    __syncthreads();
    float M = fmaxf(sm[0], sm[1]);

    float s = wave_reduce_sum(p.y * expf(p.x - M));
    __shared__ float s2[2];
    if ((tid & 63) == 0) s2[tid >> 6] = s;
    __syncthreads();
    if (tid == 0) { stats[0] = M; stats[1] = 1.f / (s2[0] + s2[1]); }
}

__global__ __launch_bounds__(256) void softmax_norm_kernel(
    const float* __restrict__ logits, const float* __restrict__ stats,
    float* __restrict__ y)
{
    const int i = blockIdx.x * 256 + threadIdx.x;
    if (i < VDIM) y[i] = expf(logits[i] - stats[0]) * stats[1];
}

extern "C" void kernel_launch(void* const* d_in, const int* in_sizes, int n_in,
                              void* d_out, int out_size, void* d_ws, size_t ws_size,
                              hipStream_t stream)
{
    const float* prev_h = (const float*)d_in[0];
    const float* prev_c = (const float*)d_in[1];
    const float* x_t    = (const float*)d_in[2];
    const float* w_xf   = (const float*)d_in[3];
    const float* w_hf   = (const float*)d_in[4];
    const float* b_f    = (const float*)d_in[5];
    const float* w_xi   = (const float*)d_in[6];
    const float* w_hi   = (const float*)d_in[7];
    const float* b_i    = (const float*)d_in[8];
    const float* w_xg   = (const float*)d_in[9];
    const float* w_hg   = (const float*)d_in[10];
    const float* b_g    = (const float*)d_in[11];
    const float* w_xo   = (const float*)d_in[12];
    const float* w_ho   = (const float*)d_in[13];
    const float* b_o    = (const float*)d_in[14];
    const float* w_hy   = (const float*)d_in[15];
    const float* b_y    = (const float*)d_in[16];

    float* out = (float*)d_out;
    float* h_t = out;              // [0, H)
    float* y_t = out + 2 * HDIM;   // [2H, 2H+V)

    float*  logits = (float*)d_ws;            // V floats
    float*  stats  = logits + VDIM;           // 2 floats
    float2* part   = (float2*)(stats + 2);    // NPART float2

    lstm_gates_kernel<<<HDIM, 256, 0, stream>>>(
        prev_h, prev_c, x_t,
        w_xf, w_hf, b_f, w_xi, w_hi, b_i,
        w_xg, w_hg, b_g, w_xo, w_ho, b_o, out);

    logits_kernel<<<VDIM / 4, 256, 0, stream>>>(w_hy, b_y, h_t, logits);

    softmax_partial_kernel<<<NPART, 256, 0, stream>>>(logits, part);

    softmax_combine_kernel<<<1, 128, 0, stream>>>(part, stats);

    softmax_norm_kernel<<<(VDIM + 255) / 256, 256, 0, stream>>>(logits, stats, y_t);
}

// Round 4
// 185.904 us; speedup vs baseline: 1.0554x; 1.0240x over previous
//
#include <hip/hip_runtime.h>
#include <math.h>

#define HDIM 4096
#define VDIM 32000
#define GBLK (HDIM / 4)    // 1024 gate blocks, 4 rows each
#define LBLK (VDIM / 16)   // 2000 logit blocks, 16 rows each

typedef float floatx4 __attribute__((ext_vector_type(4)));

__device__ inline float wave_reduce_sum(float v) {
    #pragma unroll
    for (int off = 32; off > 0; off >>= 1)
        v += __shfl_down(v, off, 64);
    return v;
}

__device__ inline floatx4 ntload4(const float* p) {
    return __builtin_nontemporal_load(reinterpret_cast<const floatx4*>(p));
}

__device__ inline float dot4(floatx4 a, floatx4 b) {
    return a.x * b.x + a.y * b.y + a.z * b.z + a.w * b.w;
}

// 1024 blocks x 256 threads. Block b owns rows [4b, 4b+4). Wave g computes
// gate g for all 4 rows (8 independent weight streams -> deep MLP).
__global__ __launch_bounds__(256) void lstm_gates_kernel(
    const float* __restrict__ prev_h, const float* __restrict__ prev_c,
    const float* __restrict__ x_t,
    const float* __restrict__ w_xf, const float* __restrict__ w_hf, const float* __restrict__ b_f,
    const float* __restrict__ w_xi, const float* __restrict__ w_hi, const float* __restrict__ b_i,
    const float* __restrict__ w_xg, const float* __restrict__ w_hg, const float* __restrict__ b_g,
    const float* __restrict__ w_xo, const float* __restrict__ w_ho, const float* __restrict__ b_o,
    float* __restrict__ out)
{
    __shared__ float s_x[HDIM];
    __shared__ float s_h[HDIM];
    __shared__ float sg[4][4];   // [gate][row]
    for (int i = threadIdx.x * 4; i < HDIM; i += 256 * 4) {
        *reinterpret_cast<float4*>(&s_x[i]) = *reinterpret_cast<const float4*>(&x_t[i]);
        *reinterpret_cast<float4*>(&s_h[i]) = *reinterpret_cast<const float4*>(&prev_h[i]);
    }
    __syncthreads();

    const int wave = threadIdx.x >> 6;
    const int lane = threadIdx.x & 63;
    const int row0 = blockIdx.x * 4;

    const float* wx; const float* wh; const float* bb;
    if      (wave == 0) { wx = w_xf; wh = w_hf; bb = b_f; }
    else if (wave == 1) { wx = w_xi; wh = w_hi; bb = b_i; }
    else if (wave == 2) { wx = w_xg; wh = w_hg; bb = b_g; }
    else                { wx = w_xo; wh = w_ho; bb = b_o; }
    wx += (size_t)row0 * HDIM;
    wh += (size_t)row0 * HDIM;

    float acc[4] = {0.f, 0.f, 0.f, 0.f};
    for (int j = lane * 4; j < HDIM; j += 64 * 4) {
        floatx4 v = *reinterpret_cast<const floatx4*>(&s_x[j]);
        floatx4 u = *reinterpret_cast<const floatx4*>(&s_h[j]);
        #pragma unroll
        for (int r = 0; r < 4; ++r) {
            floatx4 a = ntload4(wx + (size_t)r * HDIM + j);
            floatx4 b = ntload4(wh + (size_t)r * HDIM + j);
            acc[r] += dot4(a, v) + dot4(b, u);
        }
    }
    #pragma unroll
    for (int r = 0; r < 4; ++r) {
        float s = wave_reduce_sum(acc[r]);
        if (lane == 0) sg[wave][r] = s + bb[row0 + r];
    }
    __syncthreads();

    if (threadIdx.x < 4) {
        const int r   = threadIdx.x;
        const int row = row0 + r;
        float ft = 1.f / (1.f + expf(-sg[0][r]));
        float it = 1.f / (1.f + expf(-sg[1][r]));
        float gt = tanhf(sg[2][r]);
        float ot = 1.f / (1.f + expf(-sg[3][r]));
        float c  = ft * prev_c[row] + it * gt;
        float h  = ot * tanhf(c);
        out[row]        = h;   // h_t
        out[HDIM + row] = c;   // c_t
    }
}

// 2000 blocks x 256 threads. Block b owns rows [16b, 16b+16); wave w computes
// rows 16b+4w .. +3 with 4 streams. Block also emits its softmax partial.
__global__ __launch_bounds__(256) void logits_kernel(
    const float* __restrict__ w_hy, const float* __restrict__ b_y,
    const float* __restrict__ h, float* __restrict__ logits,
    float2* __restrict__ part)
{
    __shared__ float s_h[HDIM];
    __shared__ float sl[16];
    for (int i = threadIdx.x * 4; i < HDIM; i += 256 * 4)
        *reinterpret_cast<float4*>(&s_h[i]) = *reinterpret_cast<const float4*>(&h[i]);
    __syncthreads();

    const int wave = threadIdx.x >> 6;
    const int lane = threadIdx.x & 63;
    const int row0 = blockIdx.x * 16 + wave * 4;
    const float* w = w_hy + (size_t)row0 * HDIM;

    float acc[4] = {0.f, 0.f, 0.f, 0.f};
    for (int j = lane * 4; j < HDIM; j += 64 * 4) {
        floatx4 u = *reinterpret_cast<const floatx4*>(&s_h[j]);
        #pragma unroll
        for (int r = 0; r < 4; ++r) {
            floatx4 a = ntload4(w + (size_t)r * HDIM + j);
            acc[r] += dot4(a, u);
        }
    }
    #pragma unroll
    for (int r = 0; r < 4; ++r) {
        float s = wave_reduce_sum(acc[r]);
        if (lane == 0) {
            float lv = s + b_y[row0 + r];
            logits[row0 + r] = lv;
            sl[wave * 4 + r] = lv;
        }
    }
    __syncthreads();

    if (threadIdx.x < 16) {
        float v = sl[threadIdx.x];
        float m = v;
        #pragma unroll
        for (int off = 8; off > 0; off >>= 1)
            m = fmaxf(m, __shfl_xor(m, off, 64));
        float e = expf(v - m);
        #pragma unroll
        for (int off = 8; off > 0; off >>= 1)
            e += __shfl_xor(e, off, 64);
        if (threadIdx.x == 0) part[blockIdx.x] = make_float2(m, e);
    }
}

// 1 block, 1024 threads: combine LBLK partials -> stats[0]=max, stats[1]=1/sum
__global__ __launch_bounds__(1024) void softmax_combine_kernel(
    const float2* __restrict__ part, float* __restrict__ stats)
{
    const int tid  = threadIdx.x;
    const int wave = tid >> 6;
    const int lane = tid & 63;

    float m = -1e30f, s = 0.f;
    for (int i = tid; i < LBLK; i += 1024) {
        float2 p = part[i];
        if (p.x > m) { s = s * expf(m - p.x) + p.y; m = p.x; }
        else         { s += p.y * expf(p.x - m); }
    }

    __shared__ float sm[16];
    float mm = m;
    #pragma unroll
    for (int off = 32; off > 0; off >>= 1)
        mm = fmaxf(mm, __shfl_xor(mm, off, 64));
    if (lane == 0) sm[wave] = mm;
    __syncthreads();
    float M = sm[0];
    #pragma unroll
    for (int i = 1; i < 16; ++i) M = fmaxf(M, sm[i]);

    float sc = s * expf(m - M);
    #pragma unroll
    for (int off = 32; off > 0; off >>= 1)
        sc += __shfl_xor(sc, off, 64);
    __shared__ float ss[16];
    if (lane == 0) ss[wave] = sc;
    __syncthreads();
    if (tid == 0) {
        float S = 0.f;
        #pragma unroll
        for (int i = 0; i < 16; ++i) S += ss[i];
        stats[0] = M;
        stats[1] = 1.f / S;
    }
}

// float4 normalize: 8000 lanes cover 32000 outputs
__global__ __launch_bounds__(256) void softmax_norm_kernel(
    const float* __restrict__ logits, const float* __restrict__ stats,
    float* __restrict__ y)
{
    const int idx = blockIdx.x * 256 + threadIdx.x;
    if (idx < VDIM / 4) {
        float  M = stats[0], R = stats[1];
        float4 l = *reinterpret_cast<const float4*>(logits + idx * 4);
        float4 o;
        o.x = expf(l.x - M) * R;
        o.y = expf(l.y - M) * R;
        o.z = expf(l.z - M) * R;
        o.w = expf(l.w - M) * R;
        *reinterpret_cast<float4*>(y + idx * 4) = o;
    }
}

extern "C" void kernel_launch(void* const* d_in, const int* in_sizes, int n_in,
                              void* d_out, int out_size, void* d_ws, size_t ws_size,
                              hipStream_t stream)
{
    const float* prev_h = (const float*)d_in[0];
    const float* prev_c = (const float*)d_in[1];
    const float* x_t    = (const float*)d_in[2];
    const float* w_xf   = (const float*)d_in[3];
    const float* w_hf   = (const float*)d_in[4];
    const float* b_f    = (const float*)d_in[5];
    const float* w_xi   = (const float*)d_in[6];
    const float* w_hi   = (const float*)d_in[7];
    const float* b_i    = (const float*)d_in[8];
    const float* w_xg   = (const float*)d_in[9];
    const float* w_hg   = (const float*)d_in[10];
    const float* b_g    = (const float*)d_in[11];
    const float* w_xo   = (const float*)d_in[12];
    const float* w_ho   = (const float*)d_in[13];
    const float* b_o    = (const float*)d_in[14];
    const float* w_hy   = (const float*)d_in[15];
    const float* b_y    = (const float*)d_in[16];

    float* out = (float*)d_out;
    float* h_t = out;              // [0, H)
    float* y_t = out + 2 * HDIM;   // [2H, 2H+V)

    float*  logits = (float*)d_ws;            // V floats
    float*  stats  = logits + VDIM;           // 2 floats
    float2* part   = (float2*)(stats + 2);    // LBLK float2

    lstm_gates_kernel<<<GBLK, 256, 0, stream>>>(
        prev_h, prev_c, x_t,
        w_xf, w_hf, b_f, w_xi, w_hi, b_i,
        w_xg, w_hg, b_g, w_xo, w_ho, b_o, out);

    logits_kernel<<<LBLK, 256, 0, stream>>>(w_hy, b_y, h_t, logits, part);

    softmax_combine_kernel<<<1, 1024, 0, stream>>>(part, stats);

    softmax_norm_kernel<<<(VDIM / 4 + 255) / 256, 256, 0, stream>>>(logits, stats, y_t);
}